// Round 1
// baseline (1146.433 us; speedup 1.0000x reference)
//
#include <hip/hip_runtime.h>

#define N_PTS 16384
#define TOTP  32768          // B*N
#define FD    128
#define KNB   4
#define NROWS (TOTP*KNB)     // 131072

__device__ __forceinline__ float bf2f(unsigned short u) {
    union { unsigned int i; float f; } v; v.i = ((unsigned int)u) << 16; return v.f;
}
__device__ __forceinline__ unsigned short f2bf(float f) {
    union { float f; unsigned int i; } v; v.f = f;
    unsigned int u = v.i;
    u = u + 0x7FFFu + ((u >> 16) & 1u);   // RNE
    return (unsigned short)(u >> 16);
}

// fproj[p][j] = b0[j] + sum_i feat[p][i] * W0[3+i][j]
// feat = (relu(pcl@Wf1+bf1))@Wf2 + bf2   (no relu on 2nd layer)
__global__ __launch_bounds__(256, 2) void fproj_kernel(
    const float* __restrict__ pcl, const float* __restrict__ Wf1,
    const float* __restrict__ bf1, const float* __restrict__ Wf2,
    const float* __restrict__ bf2, const float* __restrict__ W0,
    const float* __restrict__ b0, unsigned short* __restrict__ fproj)
{
    __shared__ unsigned short w2[FD*FD];    // 32 KB
    __shared__ unsigned short w0p[FD*FD];   // 32 KB
    __shared__ float tbuf[16][FD];          // 8 KB
    __shared__ float fbuf[16][FD];          // 8 KB
    int tid = threadIdx.x;
    for (int idx = tid; idx < FD*FD; idx += 256) {
        w2[idx]  = f2bf(Wf2[idx]);
        w0p[idx] = f2bf(W0[3*FD + idx]);
    }
    __syncthreads();
    int j = tid & 127, g = tid >> 7;
    float wf1_0 = Wf1[0*FD+j], wf1_1 = Wf1[1*FD+j], wf1_2 = Wf1[2*FD+j];
    float bf1j = bf1[j], bf2j = bf2[j], b0j = b0[j];

    for (int base = blockIdx.x*16; base < TOTP; base += gridDim.x*16) {
        #pragma unroll
        for (int q = 0; q < 8; ++q) {
            int p = base + g*8 + q;
            float t = bf1j + pcl[p*3+0]*wf1_0 + pcl[p*3+1]*wf1_1 + pcl[p*3+2]*wf1_2;
            tbuf[g*8+q][j] = fmaxf(t, 0.f);
        }
        __syncthreads();
        float acc[8];
        #pragma unroll
        for (int q = 0; q < 8; ++q) acc[q] = bf2j;
        for (int i = 0; i < FD; i += 4) {
            float wv0 = bf2f(w2[(i+0)*FD+j]);
            float wv1 = bf2f(w2[(i+1)*FD+j]);
            float wv2 = bf2f(w2[(i+2)*FD+j]);
            float wv3 = bf2f(w2[(i+3)*FD+j]);
            #pragma unroll
            for (int q = 0; q < 8; ++q) {
                float4 h4 = *reinterpret_cast<const float4*>(&tbuf[g*8+q][i]);
                acc[q] += h4.x*wv0 + h4.y*wv1 + h4.z*wv2 + h4.w*wv3;
            }
        }
        __syncthreads();
        #pragma unroll
        for (int q = 0; q < 8; ++q) fbuf[g*8+q][j] = acc[q];
        __syncthreads();
        #pragma unroll
        for (int q = 0; q < 8; ++q) acc[q] = b0j;
        for (int i = 0; i < FD; i += 4) {
            float wv0 = bf2f(w0p[(i+0)*FD+j]);
            float wv1 = bf2f(w0p[(i+1)*FD+j]);
            float wv2 = bf2f(w0p[(i+2)*FD+j]);
            float wv3 = bf2f(w0p[(i+3)*FD+j]);
            #pragma unroll
            for (int q = 0; q < 8; ++q) {
                float4 h4 = *reinterpret_cast<const float4*>(&fbuf[g*8+q][i]);
                acc[q] += h4.x*wv0 + h4.y*wv1 + h4.z*wv2 + h4.w*wv3;
            }
        }
        #pragma unroll
        for (int q = 0; q < 8; ++q)
            fproj[(size_t)(base + g*8 + q)*FD + j] = f2bf(acc[q]);
        __syncthreads();
    }
}

// One denoise step: dst (pre-initialized to cur) += s * scatter(grad)
__global__ __launch_bounds__(256, 2) void step_kernel(
    const float* __restrict__ cur, const float* __restrict__ noisy,
    const unsigned short* __restrict__ fproj,
    const float* __restrict__ W0, const float* __restrict__ Wb,
    const float* __restrict__ bb, const float* __restrict__ Wo,
    const float* __restrict__ bo, float* __restrict__ dst, float s)
{
    __shared__ unsigned short wbs[2*FD*FD];  // 64 KB bf16 Wb
    __shared__ float hbuf[32][FD];           // 16 KB
    int tid = threadIdx.x;
    for (int idx = tid; idx < 2*FD*FD; idx += 256) wbs[idx] = f2bf(Wb[idx]);
    __syncthreads();
    int j = tid & 127, g = tid >> 7;
    float w00 = W0[0*FD+j], w01 = W0[1*FD+j], w02 = W0[2*FD+j];
    float bb0 = bb[j], bb1 = bb[FD+j];
    // epilogue mapping: 8 lanes per row
    int er = tid >> 3, ep = tid & 7, jb = ep*16;
    float wo[48];
    #pragma unroll
    for (int e = 0; e < 16; ++e) {
        wo[e*3+0] = Wo[(jb+e)*3+0];
        wo[e*3+1] = Wo[(jb+e)*3+1];
        wo[e*3+2] = Wo[(jb+e)*3+2];
    }
    float bo0 = bo[0], bo1 = bo[1], bo2 = bo[2];

    for (int base = blockIdx.x*32; base < NROWS; base += gridDim.x*32) {
        // ---- h0 = relu(cent @ W0[:3] + fproj) ----
        #pragma unroll
        for (int q = 0; q < 16; ++q) {
            int r  = g*16 + q;
            int rg = base + r;
            int p  = rg >> 2;
            int k  = rg & 3;
            int b  = p >> 14;            // / N_PTS
            int n  = p & (N_PTS - 1);
            int nb = n + k - 2;
            nb = nb < 0 ? 0 : (nb > N_PTS-1 ? N_PTS-1 : nb);
            int pn = (b << 14) + nb;
            float c0 = cur[pn*3+0] - noisy[p*3+0];
            float c1 = cur[pn*3+1] - noisy[p*3+1];
            float c2 = cur[pn*3+2] - noisy[p*3+2];
            float u = bf2f(fproj[(size_t)p*FD + j]) + c0*w00 + c1*w01 + c2*w02;
            hbuf[r][j] = fmaxf(u, 0.f);
        }
        __syncthreads();
        // ---- 2 residual blocks: h += relu(h @ Wb[l] + bb[l]) ----
        #pragma unroll 1
        for (int l = 0; l < 2; ++l) {
            const unsigned short* w = &wbs[l*FD*FD];
            float bbj = l ? bb1 : bb0;
            float acc[16];
            #pragma unroll
            for (int q = 0; q < 16; ++q) acc[q] = bbj;
            for (int i = 0; i < FD; i += 4) {
                float wv0 = bf2f(w[(i+0)*FD+j]);
                float wv1 = bf2f(w[(i+1)*FD+j]);
                float wv2 = bf2f(w[(i+2)*FD+j]);
                float wv3 = bf2f(w[(i+3)*FD+j]);
                #pragma unroll
                for (int q = 0; q < 16; ++q) {
                    float4 h4 = *reinterpret_cast<const float4*>(&hbuf[g*16+q][i]);
                    acc[q] += h4.x*wv0 + h4.y*wv1 + h4.z*wv2 + h4.w*wv3;
                }
            }
            __syncthreads();
            #pragma unroll
            for (int q = 0; q < 16; ++q) hbuf[g*16+q][j] += fmaxf(acc[q], 0.f);
            __syncthreads();
        }
        // ---- grad = h @ Wo + bo ; scatter s*grad ----
        {
            float g0 = 0.f, g1 = 0.f, g2 = 0.f;
            #pragma unroll
            for (int e = 0; e < 16; e += 4) {
                float4 h4 = *reinterpret_cast<const float4*>(&hbuf[er][jb+e]);
                g0 += h4.x*wo[(e+0)*3+0] + h4.y*wo[(e+1)*3+0] + h4.z*wo[(e+2)*3+0] + h4.w*wo[(e+3)*3+0];
                g1 += h4.x*wo[(e+0)*3+1] + h4.y*wo[(e+1)*3+1] + h4.z*wo[(e+2)*3+1] + h4.w*wo[(e+3)*3+1];
                g2 += h4.x*wo[(e+0)*3+2] + h4.y*wo[(e+1)*3+2] + h4.z*wo[(e+2)*3+2] + h4.w*wo[(e+3)*3+2];
            }
            #pragma unroll
            for (int off = 4; off; off >>= 1) {
                g0 += __shfl_down(g0, off);
                g1 += __shfl_down(g1, off);
                g2 += __shfl_down(g2, off);
            }
            if (ep == 0) {
                int rg = base + er;
                int p = rg >> 2, k = rg & 3;
                int b = p >> 14, n = p & (N_PTS - 1);
                int nb = n + k - 2;
                nb = nb < 0 ? 0 : (nb > N_PTS-1 ? N_PTS-1 : nb);
                int pn = (b << 14) + nb;
                atomicAdd(&dst[pn*3+0], s*(g0 + bo0));
                atomicAdd(&dst[pn*3+1], s*(g1 + bo1));
                atomicAdd(&dst[pn*3+2], s*(g2 + bo2));
            }
        }
        __syncthreads();
    }
}

extern "C" void kernel_launch(void* const* d_in, const int* in_sizes, int n_in,
                              void* d_out, int out_size, void* d_ws, size_t ws_size,
                              hipStream_t stream) {
    const float* pcl = (const float*)d_in[0];
    const float* Wf1 = (const float*)d_in[1];
    const float* bf1 = (const float*)d_in[2];
    const float* Wf2 = (const float*)d_in[3];
    const float* bf2 = (const float*)d_in[4];
    const float* W0  = (const float*)d_in[5];
    const float* b0  = (const float*)d_in[6];
    const float* Wb  = (const float*)d_in[7];
    const float* bb  = (const float*)d_in[8];
    const float* Wo  = (const float*)d_in[9];
    const float* bo  = (const float*)d_in[10];
    float* out = (float*)d_out;

    char* ws = (char*)d_ws;
    unsigned short* fproj = (unsigned short*)ws;              // TOTP*FD*2  = 8.4 MB
    float* bufA = (float*)(ws + (size_t)TOTP*FD*2);           // TOTP*3*4
    float* bufB = bufA + (size_t)TOTP*3;
    size_t pbytes = (size_t)TOTP*3*sizeof(float);

    fproj_kernel<<<512, 256, 0, stream>>>(pcl, Wf1, bf1, Wf2, bf2, W0, b0, fproj);

    float s = 0.2f;
    hipMemcpyAsync(bufA, pcl, pbytes, hipMemcpyDeviceToDevice, stream);
    step_kernel<<<512, 256, 0, stream>>>(pcl,  pcl, fproj, W0, Wb, bb, Wo, bo, bufA, s);
    s *= 0.95f;
    hipMemcpyAsync(bufB, bufA, pbytes, hipMemcpyDeviceToDevice, stream);
    step_kernel<<<512, 256, 0, stream>>>(bufA, pcl, fproj, W0, Wb, bb, Wo, bo, bufB, s);
    s *= 0.95f;
    hipMemcpyAsync(bufA, bufB, pbytes, hipMemcpyDeviceToDevice, stream);
    step_kernel<<<512, 256, 0, stream>>>(bufB, pcl, fproj, W0, Wb, bb, Wo, bo, bufA, s);
    s *= 0.95f;
    hipMemcpyAsync(out, bufA, pbytes, hipMemcpyDeviceToDevice, stream);
    step_kernel<<<512, 256, 0, stream>>>(bufA, pcl, fproj, W0, Wb, bb, Wo, bo, out, s);
}

// Round 2
// 242.065 us; speedup vs baseline: 4.7360x; 4.7360x over previous
//
#include <hip/hip_runtime.h>

#define NPT   16384
#define TOTP  32768          // B*N
#define FD    128
#define NROWS (TOTP*4)       // 131072

typedef unsigned short u16;
typedef __attribute__((ext_vector_type(8))) short bf16x8;
typedef __attribute__((ext_vector_type(4))) float f32x4;

__device__ __forceinline__ float bf2f(u16 u) {
    union { unsigned int i; float f; } v; v.i = ((unsigned int)u) << 16; return v.f;
}
__device__ __forceinline__ u16 f2bf(float f) {
    union { float f; unsigned int i; } v; v.f = f;
    unsigned int u = v.i;
    u = u + 0x7FFFu + ((u >> 16) & 1u);   // RNE
    return (u16)(u >> 16);
}

// ---------------------------------------------------------------------------
// fproj[p][j] = b0[j] + feat[p] @ W0[3:]     (feat = relu(pcl@Wf1+bf1)@Wf2+bf2)
// MFMA wave-tile: M=32 points per wave, barrier-free after weight staging.
// ---------------------------------------------------------------------------
__global__ __launch_bounds__(256, 1) void fproj_mfma(
    const float* __restrict__ pcl, const float* __restrict__ Wf1,
    const float* __restrict__ bf1, const float* __restrict__ Wf2,
    const float* __restrict__ bf2, const float* __restrict__ W0,
    const float* __restrict__ b0, u16* __restrict__ fproj)
{
    __shared__ __align__(16) u16 wAf[16384];   // Wf2 B-frags, 32 KB
    __shared__ __align__(16) u16 wBf[16384];   // W0[3:] B-frags, 32 KB
    __shared__ __align__(16) u16 hls[4*4096];  // per-wave h tiles, 32 KB
    const int tid = threadIdx.x;
    for (int idx = tid; idx < 16384; idx += 256) {
        int f  = idx >> 9, r2 = idx & 511;
        int ll = r2 >> 3,  e  = r2 & 7;
        int nt = f >> 2,   kk = f & 3;
        int k  = kk*32 + (ll>>4)*8 + e;
        int n  = nt*16 + (ll&15);
        wAf[idx] = f2bf(Wf2[k*FD + n]);
        wBf[idx] = f2bf(W0[(3+k)*FD + n]);
    }
    __syncthreads();
    const int wid = tid >> 6, l = tid & 63;
    const int l15 = l & 15, l4 = l >> 4;
    u16* hw = &hls[wid*4096];

    float wf1c[3][8], bf1v[8], bf2v[8], b0v[8];
    #pragma unroll
    for (int nt = 0; nt < 8; ++nt) {
        int col = nt*16 + l15;
        wf1c[0][nt] = Wf1[0*FD+col];
        wf1c[1][nt] = Wf1[1*FD+col];
        wf1c[2][nt] = Wf1[2*FD+col];
        bf1v[nt] = bf1[col];
        bf2v[nt] = bf2[col];
        b0v[nt]  = b0[col];
    }

    for (int tile = blockIdx.x; tile < TOTP/128; tile += gridDim.x) {
        int pt0 = tile*128 + wid*32;
        float px[2][4], py[2][4], pz[2][4];
        #pragma unroll
        for (int rt = 0; rt < 2; ++rt)
            #pragma unroll
            for (int reg = 0; reg < 4; ++reg) {
                int p = pt0 + rt*16 + l4*4 + reg;
                px[rt][reg] = pcl[p*3+0];
                py[rt][reg] = pcl[p*3+1];
                pz[rt][reg] = pcl[p*3+2];
            }
        // layer1: t = relu(pcl@Wf1+bf1) -> LDS (C-layout lanes, swizzled row-major)
        #pragma unroll
        for (int rt = 0; rt < 2; ++rt)
            #pragma unroll
            for (int nt = 0; nt < 8; ++nt)
                #pragma unroll
                for (int reg = 0; reg < 4; ++reg) {
                    float t = bf1v[nt] + px[rt][reg]*wf1c[0][nt]
                            + py[rt][reg]*wf1c[1][nt] + pz[rt][reg]*wf1c[2][nt];
                    t = fmaxf(t, 0.f);
                    int row = rt*16 + l4*4 + reg;
                    int cb  = (row*256 + (nt*16+l15)*2) ^ ((row&7)<<4);
                    *(u16*)((char*)hw + cb) = f2bf(t);
                }
        // GEMM1: feat = t @ Wf2 + bf2   (no relu)
        float hc[2][8][4];
        {
            bf16x8 a[2][4];
            #pragma unroll
            for (int rt = 0; rt < 2; ++rt)
                #pragma unroll
                for (int kk = 0; kk < 4; ++kk) {
                    int row = rt*16 + l15;
                    int cb  = (row*256 + l4*16 + kk*64) ^ ((row&7)<<4);
                    a[rt][kk] = *(const bf16x8*)((const char*)hw + cb);
                }
            #pragma unroll
            for (int nt = 0; nt < 8; ++nt) {
                f32x4 acc0 = {bf2v[nt],bf2v[nt],bf2v[nt],bf2v[nt]};
                f32x4 acc1 = acc0;
                #pragma unroll
                for (int kk = 0; kk < 4; ++kk) {
                    bf16x8 bfr = *(const bf16x8*)&wAf[((nt*4+kk)*64 + l)*8];
                    acc0 = __builtin_amdgcn_mfma_f32_16x16x32_bf16(a[0][kk], bfr, acc0, 0,0,0);
                    acc1 = __builtin_amdgcn_mfma_f32_16x16x32_bf16(a[1][kk], bfr, acc1, 0,0,0);
                }
                #pragma unroll
                for (int reg = 0; reg < 4; ++reg) {
                    hc[0][nt][reg] = acc0[reg];
                    hc[1][nt][reg] = acc1[reg];
                }
            }
        }
        // feat -> LDS
        #pragma unroll
        for (int rt = 0; rt < 2; ++rt)
            #pragma unroll
            for (int nt = 0; nt < 8; ++nt)
                #pragma unroll
                for (int reg = 0; reg < 4; ++reg) {
                    int row = rt*16 + l4*4 + reg;
                    int cb  = (row*256 + (nt*16+l15)*2) ^ ((row&7)<<4);
                    *(u16*)((char*)hw + cb) = f2bf(hc[rt][nt][reg]);
                }
        // GEMM2: fproj = feat @ W0[3:] + b0 -> global bf16
        {
            bf16x8 a[2][4];
            #pragma unroll
            for (int rt = 0; rt < 2; ++rt)
                #pragma unroll
                for (int kk = 0; kk < 4; ++kk) {
                    int row = rt*16 + l15;
                    int cb  = (row*256 + l4*16 + kk*64) ^ ((row&7)<<4);
                    a[rt][kk] = *(const bf16x8*)((const char*)hw + cb);
                }
            #pragma unroll
            for (int nt = 0; nt < 8; ++nt) {
                f32x4 acc0 = {b0v[nt],b0v[nt],b0v[nt],b0v[nt]};
                f32x4 acc1 = acc0;
                #pragma unroll
                for (int kk = 0; kk < 4; ++kk) {
                    bf16x8 bfr = *(const bf16x8*)&wBf[((nt*4+kk)*64 + l)*8];
                    acc0 = __builtin_amdgcn_mfma_f32_16x16x32_bf16(a[0][kk], bfr, acc0, 0,0,0);
                    acc1 = __builtin_amdgcn_mfma_f32_16x16x32_bf16(a[1][kk], bfr, acc1, 0,0,0);
                }
                #pragma unroll
                for (int reg = 0; reg < 4; ++reg) {
                    int p0 = pt0 + l4*4 + reg;
                    int p1 = pt0 + 16 + l4*4 + reg;
                    fproj[(size_t)p0*FD + nt*16 + l15] = f2bf(acc0[reg]);
                    fproj[(size_t)p1*FD + nt*16 + l15] = f2bf(acc1[reg]);
                }
            }
        }
    }
}

// ---------------------------------------------------------------------------
// One denoise step. dst pre-initialized to cur; dst += s * scatter(grad).
// Wave-tile: 32 rows = 8 points x 4 neighbors. Barrier-free after staging.
// ---------------------------------------------------------------------------
__global__ __launch_bounds__(256, 1) void step_mfma(
    const float* __restrict__ cur, const float* __restrict__ noisy,
    const u16* __restrict__ fproj,
    const float* __restrict__ W0, const float* __restrict__ Wb,
    const float* __restrict__ bb, const float* __restrict__ Wo,
    const float* __restrict__ bo, float* __restrict__ dst, float s)
{
    __shared__ __align__(16) u16 wbf[32768];   // Wb B-frags (2 layers), 64 KB
    __shared__ __align__(16) u16 hls[4*4096];  // per-wave h tiles, 32 KB
    const int tid = threadIdx.x;
    for (int idx = tid; idx < 32768; idx += 256) {
        int layer = idx >> 14, rem = idx & 16383;
        int f  = rem >> 9, r2 = rem & 511;
        int ll = r2 >> 3,  e  = r2 & 7;
        int nt = f >> 2,   kk = f & 3;
        int k  = kk*32 + (ll>>4)*8 + e;
        int n  = nt*16 + (ll&15);
        wbf[idx] = f2bf(Wb[layer*FD*FD + k*FD + n]);
    }
    __syncthreads();
    const int wid = tid >> 6, l = tid & 63;
    const int l15 = l & 15, l4 = l >> 4;
    u16* hw = &hls[wid*4096];

    float w0c[3][8], bbv[2][8], wov[8][3];
    #pragma unroll
    for (int nt = 0; nt < 8; ++nt) {
        int col = nt*16 + l15;
        w0c[0][nt] = W0[0*FD+col];
        w0c[1][nt] = W0[1*FD+col];
        w0c[2][nt] = W0[2*FD+col];
        bbv[0][nt] = bb[col];
        bbv[1][nt] = bb[FD+col];
        wov[nt][0] = Wo[col*3+0];
        wov[nt][1] = Wo[col*3+1];
        wov[nt][2] = Wo[col*3+2];
    }
    const float bo0 = bo[0], bo1 = bo[1], bo2 = bo[2];

    for (int tile = blockIdx.x; tile < NROWS/128; tile += gridDim.x) {
        int pt0 = tile*32 + wid*8;     // 8 points per wave, 4 rows each
        float hc[2][8][4];             // [rt][nt][reg]; row=rt*16+l4*4+reg, col=nt*16+l15
        // ---- layer0: h0 = relu(cent@W0[:3] + fproj) ----
        #pragma unroll
        for (int rt = 0; rt < 2; ++rt) {
            int p = pt0 + rt*4 + l4;
            int b = p >> 14, n = p & (NPT-1);
            float nx = noisy[p*3+0], ny = noisy[p*3+1], nz = noisy[p*3+2];
            float cx[4], cy[4], cz[4];
            #pragma unroll
            for (int k = 0; k < 4; ++k) {
                int nb = n + k - 2;
                nb = nb < 0 ? 0 : (nb > NPT-1 ? NPT-1 : nb);
                int pn = (b << 14) + nb;
                cx[k] = cur[pn*3+0] - nx;
                cy[k] = cur[pn*3+1] - ny;
                cz[k] = cur[pn*3+2] - nz;
            }
            #pragma unroll
            for (int nt = 0; nt < 8; ++nt) {
                float fp = bf2f(fproj[(size_t)p*FD + nt*16 + l15]);
                #pragma unroll
                for (int reg = 0; reg < 4; ++reg) {
                    float u = fp + cx[reg]*w0c[0][nt] + cy[reg]*w0c[1][nt] + cz[reg]*w0c[2][nt];
                    u = fmaxf(u, 0.f);
                    hc[rt][nt][reg] = u;
                    int row = rt*16 + l4*4 + reg;
                    int cb  = (row*256 + (nt*16+l15)*2) ^ ((row&7)<<4);
                    *(u16*)((char*)hw + cb) = f2bf(u);
                }
            }
        }
        // ---- 2 residual blocks: h += relu(h@Wb[l]+bb[l]) ----
        #pragma unroll
        for (int layer = 0; layer < 2; ++layer) {
            bf16x8 a[2][4];
            #pragma unroll
            for (int rt = 0; rt < 2; ++rt)
                #pragma unroll
                for (int kk = 0; kk < 4; ++kk) {
                    int row = rt*16 + l15;
                    int cb  = (row*256 + l4*16 + kk*64) ^ ((row&7)<<4);
                    a[rt][kk] = *(const bf16x8*)((const char*)hw + cb);
                }
            #pragma unroll
            for (int nt = 0; nt < 8; ++nt) {
                f32x4 acc0 = {bbv[layer][nt],bbv[layer][nt],bbv[layer][nt],bbv[layer][nt]};
                f32x4 acc1 = acc0;
                #pragma unroll
                for (int kk = 0; kk < 4; ++kk) {
                    bf16x8 bfr = *(const bf16x8*)&wbf[((layer*32 + nt*4 + kk)*64 + l)*8];
                    acc0 = __builtin_amdgcn_mfma_f32_16x16x32_bf16(a[0][kk], bfr, acc0, 0,0,0);
                    acc1 = __builtin_amdgcn_mfma_f32_16x16x32_bf16(a[1][kk], bfr, acc1, 0,0,0);
                }
                #pragma unroll
                for (int reg = 0; reg < 4; ++reg) {
                    hc[0][nt][reg] += fmaxf(acc0[reg], 0.f);
                    hc[1][nt][reg] += fmaxf(acc1[reg], 0.f);
                }
            }
            if (layer == 0) {   // write h1 back for next layer's A-frags
                #pragma unroll
                for (int rt = 0; rt < 2; ++rt)
                    #pragma unroll
                    for (int nt = 0; nt < 8; ++nt)
                        #pragma unroll
                        for (int reg = 0; reg < 4; ++reg) {
                            int row = rt*16 + l4*4 + reg;
                            int cb  = (row*256 + (nt*16+l15)*2) ^ ((row&7)<<4);
                            *(u16*)((char*)hw + cb) = f2bf(hc[rt][nt][reg]);
                        }
            }
        }
        // ---- epilogue: grad = h@Wo + bo, scatter s*grad ----
        #pragma unroll
        for (int rt = 0; rt < 2; ++rt) {
            float g[4][3];
            #pragma unroll
            for (int reg = 0; reg < 4; ++reg) {
                g[reg][0] = 0.f; g[reg][1] = 0.f; g[reg][2] = 0.f;
                #pragma unroll
                for (int nt = 0; nt < 8; ++nt) {
                    g[reg][0] += hc[rt][nt][reg]*wov[nt][0];
                    g[reg][1] += hc[rt][nt][reg]*wov[nt][1];
                    g[reg][2] += hc[rt][nt][reg]*wov[nt][2];
                }
            }
            #pragma unroll
            for (int off = 1; off < 16; off <<= 1)
                #pragma unroll
                for (int reg = 0; reg < 4; ++reg) {
                    g[reg][0] += __shfl_xor(g[reg][0], off);
                    g[reg][1] += __shfl_xor(g[reg][1], off);
                    g[reg][2] += __shfl_xor(g[reg][2], off);
                }
            if (l15 == 0) {
                int p = pt0 + rt*4 + l4;
                int b = p >> 14, n = p & (NPT-1);
                #pragma unroll
                for (int reg = 0; reg < 4; ++reg) {
                    int nb = n + reg - 2;
                    nb = nb < 0 ? 0 : (nb > NPT-1 ? NPT-1 : nb);
                    int pn = (b << 14) + nb;
                    atomicAdd(&dst[pn*3+0], s*(g[reg][0] + bo0));
                    atomicAdd(&dst[pn*3+1], s*(g[reg][1] + bo1));
                    atomicAdd(&dst[pn*3+2], s*(g[reg][2] + bo2));
                }
            }
        }
    }
}

extern "C" void kernel_launch(void* const* d_in, const int* in_sizes, int n_in,
                              void* d_out, int out_size, void* d_ws, size_t ws_size,
                              hipStream_t stream) {
    const float* pcl = (const float*)d_in[0];
    const float* Wf1 = (const float*)d_in[1];
    const float* bf1 = (const float*)d_in[2];
    const float* Wf2 = (const float*)d_in[3];
    const float* bf2 = (const float*)d_in[4];
    const float* W0  = (const float*)d_in[5];
    const float* b0  = (const float*)d_in[6];
    const float* Wb  = (const float*)d_in[7];
    const float* bb  = (const float*)d_in[8];
    const float* Wo  = (const float*)d_in[9];
    const float* bo  = (const float*)d_in[10];
    float* out = (float*)d_out;

    char* ws = (char*)d_ws;
    u16*   fproj = (u16*)ws;                              // TOTP*FD*2 = 8.4 MB
    float* bufA  = (float*)(ws + (size_t)TOTP*FD*2);
    float* bufB  = bufA + (size_t)TOTP*3;
    size_t pbytes = (size_t)TOTP*3*sizeof(float);

    fproj_mfma<<<256, 256, 0, stream>>>(pcl, Wf1, bf1, Wf2, bf2, W0, b0, fproj);

    float s = 0.2f;
    hipMemcpyAsync(bufA, pcl, pbytes, hipMemcpyDeviceToDevice, stream);
    step_mfma<<<256, 256, 0, stream>>>(pcl,  pcl, fproj, W0, Wb, bb, Wo, bo, bufA, s);
    s *= 0.95f;
    hipMemcpyAsync(bufB, bufA, pbytes, hipMemcpyDeviceToDevice, stream);
    step_mfma<<<256, 256, 0, stream>>>(bufA, pcl, fproj, W0, Wb, bb, Wo, bo, bufB, s);
    s *= 0.95f;
    hipMemcpyAsync(bufA, bufB, pbytes, hipMemcpyDeviceToDevice, stream);
    step_mfma<<<256, 256, 0, stream>>>(bufB, pcl, fproj, W0, Wb, bb, Wo, bo, bufA, s);
    s *= 0.95f;
    hipMemcpyAsync(out, bufA, pbytes, hipMemcpyDeviceToDevice, stream);
    step_mfma<<<256, 256, 0, stream>>>(bufA, pcl, fproj, W0, Wb, bb, Wo, bo, out, s);
}